// Round 4
// baseline (249.066 us; speedup 1.0000x reference)
//
#include <hip/hip_runtime.h>
#include <math.h>

// Problem constants
#define NB 8
#define NN 256
#define ND 64
#define NE 64
#define NR 32
// mu_r = 20*r/31, sigma = 0.625, 1/sigma = 1.6

typedef _Float16 half8 __attribute__((ext_vector_type(8)));
typedef _Float16 half4 __attribute__((ext_vector_type(4)));
typedef __fp16 fp16x2 __attribute__((ext_vector_type(2)));
typedef float f32x4 __attribute__((ext_vector_type(4)));

__device__ __forceinline__ float rl(float x, int lane) {
    return __uint_as_float(__builtin_amdgcn_readlane(__float_as_uint(x), lane));
}

__device__ __forceinline__ float wave_sum64(float v) {
#pragma unroll
    for (int m = 32; m >= 1; m >>= 1) v += __shfl_xor(v, m, 64);
    return v;
}

__device__ __forceinline__ half4 mk4(float a, float b, float c, float d) {
    fp16x2 lo = __builtin_amdgcn_cvt_pkrtz(a, b);
    fp16x2 hi = __builtin_amdgcn_cvt_pkrtz(c, d);
    half4 r;
    r[0] = (_Float16)lo[0]; r[1] = (_Float16)lo[1];
    r[2] = (_Float16)hi[0]; r[3] = (_Float16)hi[1];
    return r;
}

// -------- K1: node path (blocks 0..511) + weight prep (blocks 512..515)
// node = LN(relu(emb[atom]) @ ne_w + ne_b); ws_s = node@Ws + b1; node_h = (f16)node
// prep: wcat[e][k] (k<32: Wr[k][e], k>=32: Wt[k-32][e]), w2tH[e2][e1]=W2^T, w3tH[e3][e2]=W3^T
__global__ __launch_bounds__(256) void k1_node(
    const int* __restrict__ atom, const float* __restrict__ emb,
    const float* __restrict__ ne_w, const float* __restrict__ ne_b,
    const float* __restrict__ ne_g, const float* __restrict__ ne_beta,
    const float* __restrict__ ee_w1, const float* __restrict__ ee_b1,
    const float* __restrict__ ee_w2, const float* __restrict__ ee_w3,
    float* __restrict__ ws_node, float* __restrict__ ws_s,
    _Float16* __restrict__ node_h, _Float16* __restrict__ wcat,
    _Float16* __restrict__ w2tH, _Float16* __restrict__ w3tH)
{
    if (blockIdx.x >= 512) {
        // ---- weight prep: 4 blocks x 256 threads
        const int tid = (blockIdx.x - 512) * 256 + threadIdx.x;   // 0..1023
        for (int idx = tid; idx < 64 * 96; idx += 1024) {         // wcat[e][k]
            const int e = idx / 96, k = idx - e * 96;
            const float v = (k < 32) ? ee_w1[(2 * ND + k) * NE + e]
                                     : ee_w1[(ND + (k - 32)) * NE + e];
            wcat[idx] = (_Float16)v;
        }
        for (int idx = tid; idx < NE * NE; idx += 1024) {         // transposes
            const int n = idx >> 6, k = idx & 63;
            w2tH[idx] = (_Float16)ee_w2[k * NE + n];
            w3tH[idx] = (_Float16)ee_w3[k * NE + n];
        }
        return;
    }

    const int wave = threadIdx.x >> 6;
    const int lane = threadIdx.x & 63;
    const int row  = blockIdx.x * 4 + wave;

    const int a = atom[row];
    float ev = fmaxf(emb[a * ND + lane], 0.f);

    float a0 = 0.f, a1 = 0.f, a2 = 0.f, a3 = 0.f;
#pragma unroll
    for (int k = 0; k < ND; k += 4) {
        a0 = fmaf(rl(ev, k + 0), ne_w[(k + 0) * ND + lane], a0);
        a1 = fmaf(rl(ev, k + 1), ne_w[(k + 1) * ND + lane], a1);
        a2 = fmaf(rl(ev, k + 2), ne_w[(k + 2) * ND + lane], a2);
        a3 = fmaf(rl(ev, k + 3), ne_w[(k + 3) * ND + lane], a3);
    }
    float pre = ne_b[lane] + ((a0 + a1) + (a2 + a3));

    float mean = wave_sum64(pre) * (1.f / 64.f);
    float dv = pre - mean;
    float var = wave_sum64(dv * dv) * (1.f / 64.f);
    float nv = dv * rsqrtf(var + 1e-5f) * ne_g[lane] + ne_beta[lane];
    ws_node[row * ND + lane] = nv;
    node_h[row * ND + lane] = (_Float16)nv;

    // s = node @ Ws + b1 (Ws = ee_w1 rows [0,64))
    float s0 = 0.f, s1 = 0.f;
#pragma unroll
    for (int k = 0; k < ND; k += 2) {
        s0 = fmaf(rl(nv, k),     ee_w1[(k)     * NE + lane], s0);
        s1 = fmaf(rl(nv, k + 1), ee_w1[(k + 1) * NE + lane], s1);
    }
    ws_s[row * NE + lane] = ee_b1[lane] + s0 + s1;
}

// -------- K2: per (b,j) block, wave w owns i in [w*64, w*64+64). Fully register-chained:
// stage1 (transposed, 16x16x32 f16, K=96): C1[e][i] = Wcat^T @ [rbf|node]^T  (+s incl b1)
// stage2 (transposed, 16x16x16 f16): C2[e2][i] = W2^T @ relu(C1)   (C1 reused as B in-register)
// stage3 (normal,     16x16x16 f16): C3[i][e3] = relu(C2)^T-as-A @ W3
// -> standard C layout -> in-register LN -> edge + agg partials.  No LDS round trips.
__global__ __launch_bounds__(256) void k2_edge(
    const float* __restrict__ pos, const float* __restrict__ mask,
    const int* __restrict__ atom,
    const float* __restrict__ ws_s, const _Float16* __restrict__ node_h,
    const _Float16* __restrict__ wcat, const _Float16* __restrict__ w2tH,
    const _Float16* __restrict__ w3tH,
    const float* __restrict__ ee_b2, const float* __restrict__ ee_b3,
    const float* __restrict__ ee_g, const float* __restrict__ ee_beta,
    float* __restrict__ edge_out, float* __restrict__ ws_agg)
{
    __shared__ float aggp[4][64];
    __shared__ float mp[4];

    const int bj = blockIdx.x;
    const int b = bj >> 8, j = bj & 255;
    const int wave = threadIdx.x >> 6, lane = threadIdx.x & 63;
    const int quad = lane >> 4, col = lane & 15;
    const int ibase = wave * 64;

    // per-lane scalar params
    float s_r[4][4], b2_r[4][4];
#pragma unroll
    for (int mt = 0; mt < 4; mt++)
#pragma unroll
        for (int r = 0; r < 4; r++) {
            const int e = mt * 16 + quad * 4 + r;
            s_r[mt][r]  = ws_s[bj * NE + e];     // includes b1 (+ s_j)
            b2_r[mt][r] = ee_b2[e];
        }
    float b3v[4], gv[4], bev[4];
#pragma unroll
    for (int nt = 0; nt < 4; nt++) {
        const int e = nt * 16 + col;
        b3v[nt] = ee_b3[e];
        gv[nt]  = ee_g[e];
        bev[nt] = ee_beta[e];
    }

    const float pjx = pos[bj * 3 + 0], pjy = pos[bj * 3 + 1], pjz = pos[bj * 3 + 2];

    // dist & mask for this lane's i columns (i = ibase + nt*16 + col)
    float dist4[4], m4[4];
#pragma unroll
    for (int nt = 0; nt < 4; nt++) {
        const int bi = b * NN + ibase + nt * 16 + col;
        const float m = mask[bi * NN + j];
        const float dx = pjx - pos[bi * 3 + 0];
        const float dy = pjy - pos[bi * 3 + 1];
        const float dz = pjz - pos[bi * 3 + 2];
        dist4[nt] = sqrtf(fmaf(dx, dx, fmaf(dy, dy, fmaf(dz, dz, 1e-10f)))) * m;
        m4[nt] = m;
    }

    float murv[8];
#pragma unroll
    for (int t = 0; t < 8; t++) murv[t] = 1.0322580645f * (float)(quad * 8 + t);  // mu_r*1.6

    // ---- stage 1: K=96 (kt0: rbf rows, kt1/2: node rows), A = wcat[e][k]
    f32x4 acc1[4][4];
#pragma unroll
    for (int mt = 0; mt < 4; mt++)
#pragma unroll
        for (int nt = 0; nt < 4; nt++) acc1[mt][nt] = (f32x4){0.f, 0.f, 0.f, 0.f};

#pragma unroll
    for (int kt = 0; kt < 3; kt++) {
        half8 bf[4];
        if (kt == 0) {
#pragma unroll
            for (int nt = 0; nt < 4; nt++) {
                const float d = dist4[nt], m = m4[nt];
                half8 v;
#pragma unroll
                for (int t = 0; t < 8; t += 2) {
                    const float u0 = fmaf(d, 1.6f, -murv[t]);
                    const float u1 = fmaf(d, 1.6f, -murv[t + 1]);
                    const float r0 = exp2f(u0 * u0 * (-1.44269504f)) * m;
                    const float r1 = exp2f(u1 * u1 * (-1.44269504f)) * m;
                    fp16x2 p = __builtin_amdgcn_cvt_pkrtz(r0, r1);
                    v[t] = (_Float16)p[0]; v[t + 1] = (_Float16)p[1];
                }
                bf[nt] = v;
            }
        } else {
#pragma unroll
            for (int nt = 0; nt < 4; nt++) {
                const int i = ibase + nt * 16 + col;
                bf[nt] = *(const half8*)(node_h + (b * NN + i) * ND + (kt - 1) * 32 + quad * 8);
            }
        }
        half8 af[4];
#pragma unroll
        for (int mt = 0; mt < 4; mt++)
            af[mt] = *(const half8*)(wcat + (mt * 16 + col) * 96 + kt * 32 + quad * 8);
#pragma unroll
        for (int mt = 0; mt < 4; mt++)
#pragma unroll
            for (int nt = 0; nt < 4; nt++)
                acc1[mt][nt] = __builtin_amdgcn_mfma_f32_16x16x32_f16(af[mt], bf[nt], acc1[mt][nt], 0, 0, 0);
    }

    // epilogue 1: + s[e], relu, pack to f16 B-frags for stage 2 (kt index = stage-1 mt)
    half4 b1f[4][4];
#pragma unroll
    for (int mt = 0; mt < 4; mt++)
#pragma unroll
        for (int nt = 0; nt < 4; nt++)
            b1f[mt][nt] = mk4(fmaxf(acc1[mt][nt][0] + s_r[mt][0], 0.f),
                              fmaxf(acc1[mt][nt][1] + s_r[mt][1], 0.f),
                              fmaxf(acc1[mt][nt][2] + s_r[mt][2], 0.f),
                              fmaxf(acc1[mt][nt][3] + s_r[mt][3], 0.f));

    // ---- stage 2: C2[e2][i] = W2^T @ H1^T
    f32x4 acc2[4][4];
#pragma unroll
    for (int mt = 0; mt < 4; mt++)
#pragma unroll
        for (int nt = 0; nt < 4; nt++) acc2[mt][nt] = (f32x4){0.f, 0.f, 0.f, 0.f};
#pragma unroll
    for (int kt = 0; kt < 4; kt++) {
        half4 a2[4];
#pragma unroll
        for (int mt = 0; mt < 4; mt++)
            a2[mt] = *(const half4*)(w2tH + (mt * 16 + col) * NE + kt * 16 + quad * 4);
#pragma unroll
        for (int mt = 0; mt < 4; mt++)
#pragma unroll
            for (int nt = 0; nt < 4; nt++)
                acc2[mt][nt] = __builtin_amdgcn_mfma_f32_16x16x16f16(a2[mt], b1f[kt][nt], acc2[mt][nt], 0, 0, 0);
    }

    // epilogue 2: + b2, relu, pack to A-frags for stage 3: a3f[i-tile][k-tile]
    half4 a3f[4][4];
#pragma unroll
    for (int mt = 0; mt < 4; mt++)
#pragma unroll
        for (int nt = 0; nt < 4; nt++)
            a3f[nt][mt] = mk4(fmaxf(acc2[mt][nt][0] + b2_r[mt][0], 0.f),
                              fmaxf(acc2[mt][nt][1] + b2_r[mt][1], 0.f),
                              fmaxf(acc2[mt][nt][2] + b2_r[mt][2], 0.f),
                              fmaxf(acc2[mt][nt][3] + b2_r[mt][3], 0.f));

    // ---- stage 3: C3[i][e3] = H2 @ W3  (normal orientation)
    f32x4 acc3[4][4];
#pragma unroll
    for (int mt = 0; mt < 4; mt++)
#pragma unroll
        for (int nt = 0; nt < 4; nt++) acc3[mt][nt] = (f32x4){0.f, 0.f, 0.f, 0.f};
#pragma unroll
    for (int kt = 0; kt < 4; kt++) {
        half4 b3f[4];
#pragma unroll
        for (int nt = 0; nt < 4; nt++)
            b3f[nt] = *(const half4*)(w3tH + (nt * 16 + col) * NE + kt * 16 + quad * 4);
#pragma unroll
        for (int mi = 0; mi < 4; mi++)
#pragma unroll
            for (int nt = 0; nt < 4; nt++)
                acc3[mi][nt] = __builtin_amdgcn_mfma_f32_16x16x16f16(a3f[mi][kt], b3f[nt], acc3[mi][nt], 0, 0, 0);
    }

    // + b3
#pragma unroll
    for (int mt = 0; mt < 4; mt++)
#pragma unroll
        for (int nt = 0; nt < 4; nt++)
#pragma unroll
            for (int r = 0; r < 4; r++)
                acc3[mt][nt][r] += b3v[nt];

    // in-register LN across e3 (row i = ibase + mt*16 + quad*4 + r)
    float meanv[4][4], rsv[4][4];
#pragma unroll
    for (int mt = 0; mt < 4; mt++)
#pragma unroll
        for (int r = 0; r < 4; r++) {
            float s = 0.f, q = 0.f;
#pragma unroll
            for (int nt = 0; nt < 4; nt++) {
                const float x = acc3[mt][nt][r];
                s += x;
                q = fmaf(x, x, q);
            }
#pragma unroll
            for (int m = 1; m <= 8; m <<= 1) {
                s += __shfl_xor(s, m, 64);
                q += __shfl_xor(q, m, 64);
            }
            const float mean = s * (1.f / 64.f);
            const float var = q * (1.f / 64.f) - mean * mean;
            meanv[mt][r] = mean;
            rsv[mt][r] = rsqrtf(var + 1e-5f);
        }

    // write edge + accumulate per-column partial sums for agg
    float ag[4] = {0.f, 0.f, 0.f, 0.f};
    float* eb = edge_out + ((size_t)(b * NN + ibase + quad * 4) * NN + j) * NE + col;
#pragma unroll
    for (int mt = 0; mt < 4; mt++)
#pragma unroll
        for (int nt = 0; nt < 4; nt++)
#pragma unroll
            for (int r = 0; r < 4; r++) {
                const float d = (acc3[mt][nt][r] - meanv[mt][r]) * rsv[mt][r];
                const float y = fmaf(d, gv[nt], bev[nt]);
                eb[(mt * 16 + r) * NN * NE + nt * 16] = y;
                ag[nt] += y;
            }

#pragma unroll
    for (int nt = 0; nt < 4; nt++) {
        ag[nt] += __shfl_xor(ag[nt], 16, 64);
        ag[nt] += __shfl_xor(ag[nt], 32, 64);
    }
    if (quad == 0) {
#pragma unroll
        for (int nt = 0; nt < 4; nt++) aggp[wave][nt * 16 + col] = ag[nt];
    }
    float msu = m4[0] + m4[1] + m4[2] + m4[3];
#pragma unroll
    for (int m = 1; m <= 8; m <<= 1) msu += __shfl_xor(msu, m, 64);
    if (lane == 0) mp[wave] = msu;

    __syncthreads();
    if (threadIdx.x < 64) {
        const int e = threadIdx.x;
        const float tot = aggp[0][e] + aggp[1][e] + aggp[2][e] + aggp[3][e];
        const float ms = mp[0] + mp[1] + mp[2] + mp[3];
        const float gate = (atom[bj] > 0) ? 1.f : 0.f;
        ws_agg[bj * NE + e] = tot / (ms + 1e-10f) * gate;
    }
}

// -------- K3: x = MLP(concat(node, agg)); out0 = node + LN(x)
__global__ __launch_bounds__(256) void k3_final(
    const float* __restrict__ ws_node, const float* __restrict__ ws_agg,
    const float* __restrict__ na_w1, const float* __restrict__ na_b1,
    const float* __restrict__ na_w2, const float* __restrict__ na_b2,
    const float* __restrict__ na_w3, const float* __restrict__ na_b3,
    const float* __restrict__ na_g, const float* __restrict__ na_beta,
    float* __restrict__ out0)
{
    const int wave = threadIdx.x >> 6;
    const int lane = threadIdx.x & 63;
    const int row = blockIdx.x * 4 + wave;

    const float nv = ws_node[row * ND + lane];
    const float av = ws_agg[row * ND + lane];

    float a0 = 0.f, a1 = 0.f, a2 = 0.f, a3 = 0.f;
#pragma unroll
    for (int k = 0; k < ND; k += 2) {
        a0 = fmaf(rl(nv, k),     na_w1[(k)     * ND + lane], a0);
        a1 = fmaf(rl(nv, k + 1), na_w1[(k + 1) * ND + lane], a1);
        a2 = fmaf(rl(av, k),     na_w1[(ND + k)     * ND + lane], a2);
        a3 = fmaf(rl(av, k + 1), na_w1[(ND + k + 1) * ND + lane], a3);
    }
    const float x1 = fmaxf(na_b1[lane] + (a0 + a1) + (a2 + a3), 0.f);

    float b0 = 0.f, b1 = 0.f, b2 = 0.f, b3 = 0.f;
#pragma unroll
    for (int k = 0; k < ND; k += 4) {
        b0 = fmaf(rl(x1, k + 0), na_w2[(k + 0) * ND + lane], b0);
        b1 = fmaf(rl(x1, k + 1), na_w2[(k + 1) * ND + lane], b1);
        b2 = fmaf(rl(x1, k + 2), na_w2[(k + 2) * ND + lane], b2);
        b3 = fmaf(rl(x1, k + 3), na_w2[(k + 3) * ND + lane], b3);
    }
    const float x2 = fmaxf(na_b2[lane] + (b0 + b1) + (b2 + b3), 0.f);

    float c0 = 0.f, c1 = 0.f, c2 = 0.f, c3 = 0.f;
#pragma unroll
    for (int k = 0; k < ND; k += 4) {
        c0 = fmaf(rl(x2, k + 0), na_w3[(k + 0) * ND + lane], c0);
        c1 = fmaf(rl(x2, k + 1), na_w3[(k + 1) * ND + lane], c1);
        c2 = fmaf(rl(x2, k + 2), na_w3[(k + 2) * ND + lane], c2);
        c3 = fmaf(rl(x2, k + 3), na_w3[(k + 3) * ND + lane], c3);
    }
    const float p3 = na_b3[lane] + (c0 + c1) + (c2 + c3);

    const float mean = wave_sum64(p3) * (1.f / 64.f);
    const float dvv = p3 - mean;
    const float var = wave_sum64(dvv * dvv) * (1.f / 64.f);
    const float x3 = dvv * rsqrtf(var + 1e-5f) * na_g[lane] + na_beta[lane];

    out0[row * ND + lane] = nv + x3;
}

extern "C" void kernel_launch(void* const* d_in, const int* in_sizes, int n_in,
                              void* d_out, int out_size, void* d_ws, size_t ws_size,
                              hipStream_t stream) {
    const int*   atom    = (const int*)d_in[0];
    const float* pos     = (const float*)d_in[1];
    const float* mask    = (const float*)d_in[2];
    const float* emb     = (const float*)d_in[3];
    const float* ne_w    = (const float*)d_in[4];
    const float* ne_b    = (const float*)d_in[5];
    const float* ne_g    = (const float*)d_in[6];
    const float* ne_beta = (const float*)d_in[7];
    const float* ee_w1   = (const float*)d_in[8];
    const float* ee_b1   = (const float*)d_in[9];
    const float* ee_w2   = (const float*)d_in[10];
    const float* ee_b2   = (const float*)d_in[11];
    const float* ee_w3   = (const float*)d_in[12];
    const float* ee_b3   = (const float*)d_in[13];
    const float* ee_g    = (const float*)d_in[14];
    const float* ee_beta = (const float*)d_in[15];
    const float* na_w1   = (const float*)d_in[16];
    const float* na_b1   = (const float*)d_in[17];
    const float* na_w2   = (const float*)d_in[18];
    const float* na_b2   = (const float*)d_in[19];
    const float* na_w3   = (const float*)d_in[20];
    const float* na_b3   = (const float*)d_in[21];
    const float* na_g    = (const float*)d_in[22];
    const float* na_beta = (const float*)d_in[23];

    float* out0     = (float*)d_out;                       // (B,N,D)
    float* edge_out = (float*)d_out + NB * NN * ND;        // (B,N,N,E)

    float* ws_node = (float*)d_ws;                         // 131072 f32
    float* ws_s    = ws_node + NB * NN * ND;               // 131072
    float* ws_agg  = ws_s + NB * NN * NE;                  // 131072
    _Float16* node_h = (_Float16*)(ws_agg + NB * NN * NE); // 131072 f16
    _Float16* wcat   = node_h + NB * NN * ND;              // 64*96
    _Float16* w2tH   = wcat + 64 * 96;                     // 4096
    _Float16* w3tH   = w2tH + NE * NE;                     // 4096

    hipLaunchKernelGGL(k1_node, dim3(516), dim3(256), 0, stream,
                       atom, emb, ne_w, ne_b, ne_g, ne_beta, ee_w1, ee_b1,
                       ee_w2, ee_w3, ws_node, ws_s, node_h, wcat, w2tH, w3tH);

    hipLaunchKernelGGL(k2_edge, dim3(NB * NN), dim3(256), 0, stream,
                       pos, mask, atom, ws_s, node_h, wcat, w2tH, w3tH,
                       ee_b2, ee_b3, ee_g, ee_beta, edge_out, ws_agg);

    hipLaunchKernelGGL(k3_final, dim3(NB * NN / 4), dim3(256), 0, stream,
                       ws_node, ws_agg, na_w1, na_b1, na_w2, na_b2, na_w3, na_b3,
                       na_g, na_beta, out0);
}